// Round 11
// baseline (196.001 us; speedup 1.0000x reference)
//
#include <hip/hip_runtime.h>

#define IN_DIM 256
#define OUT_DIM 64
#define NEG_SLOPE 0.01f
#define SCAN_CHUNK 2048
#define HBS 280  // LDS row stride (bf16 elems): 140 words = 12 mod 32 -> 2-way on frag reads AND b128 stage writes (free)

typedef short short8 __attribute__((ext_vector_type(8)));
typedef float f32x4 __attribute__((ext_vector_type(4)));
typedef unsigned short u16x8 __attribute__((ext_vector_type(8)));

__device__ __forceinline__ unsigned short f2b(float f) {  // fp32 -> bf16 RNE
    unsigned u = __float_as_uint(f);
    return (unsigned short)((u + 0x7FFFu + ((u >> 16) & 1u)) >> 16);
}
__device__ __forceinline__ float b2f(unsigned short b) {
    return __uint_as_float(((unsigned)b) << 16);
}

// ---------------- Kernel 1: z = h @ W via bf16 MFMA + fused scores; emits bf16 z ----------------
// Also zeroes deg[] (+ticket+flag) so no separate memset dispatch is needed.
__global__ __launch_bounds__(256) void gemm_mfma(const float* __restrict__ h,
                                                 const float* __restrict__ W,
                                                 const float* __restrict__ a,
                                                 unsigned short* __restrict__ zb,
                                                 float* __restrict__ s_src,
                                                 float* __restrict__ s_dst,
                                                 int* __restrict__ deg, int ndeg, int n) {
    __shared__ unsigned short hb[64 * HBS];
    __shared__ unsigned short wb[64 * HBS];
    __shared__ float sp1[2][64];
    __shared__ float sp2[2][64];
    const int tid = threadIdx.x;
    const int lane = tid & 63;
    const int w = tid >> 6;
    const int row0 = blockIdx.x * 64;

    // fused memset: zero deg[0..ndeg) across blocks (gemm completes before count_deg)
    if (tid < 66) {
        int di = blockIdx.x * 66 + tid;
        if (di < ndeg) deg[di] = 0;
    }

    // stage W -> bf16 B^T LDS: wb[c][k] = W[k][c]; lane=c -> global reads coalesced,
    // b128 LDS writes at 560B stride -> 2-way bank aliasing (free)
    {
        int c = tid & 63, kseg = tid >> 6;
        #pragma unroll
        for (int i = 0; i < 8; ++i) {
            u16x8 p;
            #pragma unroll
            for (int j = 0; j < 8; ++j) {
                int k = kseg * 64 + i * 8 + j;
                p[j] = f2b(W[(size_t)k * OUT_DIM + c]);
            }
            *(u16x8*)&wb[c * HBS + kseg * 64 + i * 8] = p;
        }
    }
    // stage h -> bf16 LDS: lane=row -> b128 writes at 560B stride (2-way, free)
    {
        int r = tid & 63, seg = tid >> 6;
        int grow = row0 + r;
        #pragma unroll
        for (int i = 0; i < 8; ++i) {
            float4 h0 = make_float4(0.f, 0.f, 0.f, 0.f);
            float4 h1 = make_float4(0.f, 0.f, 0.f, 0.f);
            if (grow < n) {
                h0 = *(const float4*)&h[(size_t)grow * IN_DIM + seg * 64 + i * 8];
                h1 = *(const float4*)&h[(size_t)grow * IN_DIM + seg * 64 + i * 8 + 4];
            }
            u16x8 p;
            p[0] = f2b(h0.x); p[1] = f2b(h0.y); p[2] = f2b(h0.z); p[3] = f2b(h0.w);
            p[4] = f2b(h1.x); p[5] = f2b(h1.y); p[6] = f2b(h1.z); p[7] = f2b(h1.w);
            *(u16x8*)&hb[r * HBS + seg * 64 + i * 8] = p;
        }
    }
    __syncthreads();

    const int rw = (w & 1) * 32;
    const int cw = (w >> 1) * 32;
    const int l16 = lane & 15;
    const int q = lane >> 4;

    f32x4 acc[2][2] = {};
    #pragma unroll
    for (int ks = 0; ks < 8; ++ks) {
        short8 af[2], bf[2];
        #pragma unroll
        for (int i = 0; i < 2; ++i)
            af[i] = *(const short8*)&hb[(rw + i * 16 + l16) * HBS + ks * 32 + q * 8];
        #pragma unroll
        for (int j = 0; j < 2; ++j)
            bf[j] = *(const short8*)&wb[(cw + j * 16 + l16) * HBS + ks * 32 + q * 8];
        #pragma unroll
        for (int i = 0; i < 2; ++i)
            #pragma unroll
            for (int j = 0; j < 2; ++j)
                acc[i][j] = __builtin_amdgcn_mfma_f32_16x16x32_bf16(af[i], bf[j], acc[i][j], 0, 0, 0);
    }

    // epilogue: write bf16 z + fused scores (C map: col = lane&15, row = (lane>>4)*4 + reg)
    #pragma unroll
    for (int i = 0; i < 2; ++i) {
        #pragma unroll
        for (int reg = 0; reg < 4; ++reg) {
            int row_local = rw + i * 16 + q * 4 + reg;
            int grow = row0 + row_local;
            float p1 = 0.f, p2 = 0.f;
            #pragma unroll
            for (int j = 0; j < 2; ++j) {
                int col = cw + j * 16 + l16;
                float zv = acc[i][j][reg];
                if (grow < n) zb[(size_t)grow * OUT_DIM + col] = f2b(zv);
                p1 = fmaf(zv, a[col], p1);
                p2 = fmaf(zv, a[OUT_DIM + col], p2);
            }
            #pragma unroll
            for (int o = 1; o < 16; o <<= 1) {
                p1 += __shfl_xor(p1, o);
                p2 += __shfl_xor(p2, o);
            }
            if (l16 == 0) {
                sp1[w >> 1][row_local] = p1;
                sp2[w >> 1][row_local] = p2;
            }
        }
    }
    __syncthreads();
    if (tid < 64) {
        int grow = row0 + tid;
        if (grow < n) {
            s_src[grow] = sp1[0][tid] + sp1[1][tid];
            s_dst[grow] = sp2[0][tid] + sp2[1][tid];
        }
    }
}

// ------------- Kernel 2: degree histogram, 4 edges/thread; atomic return = edge rank -------------
__global__ __launch_bounds__(256) void count_deg(const int* __restrict__ dst,
                                                 int* __restrict__ deg,
                                                 int* __restrict__ rank, int E) {
    int base = (blockIdx.x * 256 + threadIdx.x) * 4;
    if (base >= E) return;
    if (base + 3 < E) {
        int4 tv = *(const int4*)&dst[base];
        int4 rv;
        rv.x = atomicAdd(&deg[tv.x], 1);
        rv.y = atomicAdd(&deg[tv.y], 1);
        rv.z = atomicAdd(&deg[tv.z], 1);
        rv.w = atomicAdd(&deg[tv.w], 1);
        *(int4*)&rank[base] = rv;
    } else {
        for (int i = base; i < E; ++i) rank[i] = atomicAdd(&deg[dst[i]], 1);
    }
}

// ------------- Kernel 3: fused hierarchical scan (chunk sums + spin + local scan) -------------
// nb blocks (<= a few hundred) are all co-resident: last arriver scans chunk sums, others spin.
__global__ __launch_bounds__(256) void scan_fused(const int* __restrict__ deg,
                                                  int* __restrict__ bsum,
                                                  int* __restrict__ ebase,
                                                  int* __restrict__ offs,
                                                  int* __restrict__ ticket,
                                                  int* __restrict__ flag, int n, int nb) {
    __shared__ int ts[256];
    __shared__ int base_sh;
    const int tid = threadIdx.x;
    int base = blockIdx.x * SCAN_CHUNK + tid * 8;
    int v[8];
    int s = 0;
    #pragma unroll
    for (int j = 0; j < 8; ++j) {
        v[j] = (base + j < n) ? deg[base + j] : 0;
        s += v[j];
    }
    ts[tid] = s;
    __syncthreads();
    #pragma unroll
    for (int d = 1; d < 256; d <<= 1) {
        int add = (tid >= d) ? ts[tid - d] : 0;
        __syncthreads();
        ts[tid] += add;
        __syncthreads();
    }
    if (tid == 0) {
        bsum[blockIdx.x] = ts[255];  // chunk total
        __threadfence();
        int t = atomicAdd(ticket, 1);
        if (t == nb - 1) {  // last arriver scans the chunk sums
            int run = 0;
            for (int b = 0; b < nb; ++b) {
                int vv = atomicAdd(&bsum[b], 0);
                ebase[b] = run;
                run += vv;
            }
            offs[n] = run;  // total = E
            __threadfence();
            atomicExch(flag, 1);
        }
        while (atomicAdd(flag, 0) == 0) __builtin_amdgcn_s_sleep(8);
        base_sh = atomicAdd(&ebase[blockIdx.x], 0);
    }
    __syncthreads();
    int run = base_sh + ts[tid] - s;  // exclusive prefix for this thread
    #pragma unroll
    for (int j = 0; j < 8; ++j) {
        if (base + j < n) offs[base + j] = run;
        run += v[j];
    }
}

// ------------- Kernel 4: scatter edges into CSR, 4 edges/thread, atomic-free -------------
__global__ __launch_bounds__(256) void scatter_csr(const int* __restrict__ src,
                                                   const int* __restrict__ dst,
                                                   const float* __restrict__ s_src,
                                                   const float* __restrict__ s_dst,
                                                   const int* __restrict__ offs,
                                                   const int* __restrict__ rank,
                                                   int2* __restrict__ csr, int E) {
    int base = (blockIdx.x * 256 + threadIdx.x) * 4;
    if (base >= E) return;
    if (base + 3 < E) {
        int4 sv = *(const int4*)&src[base];
        int4 tv = *(const int4*)&dst[base];
        int4 rv = *(const int4*)&rank[base];
        #pragma unroll
        for (int k = 0; k < 4; ++k) {
            int s = (&sv.x)[k], t = (&tv.x)[k];
            float x = s_src[s] + s_dst[t];
            x = x > 0.f ? x : NEG_SLOPE * x;
            float wgt = __expf(x);  // shift-invariant softmax; scores bounded -> fp32-safe
            csr[offs[t] + (&rv.x)[k]] = make_int2(s, __float_as_int(wgt));
        }
    } else {
        for (int i = base; i < E; ++i) {
            int s = src[i], t = dst[i];
            float x = s_src[s] + s_dst[t];
            x = x > 0.f ? x : NEG_SLOPE * x;
            float wgt = __expf(x);
            csr[offs[t] + rank[i]] = make_int2(s, __float_as_int(wgt));
        }
    }
}

// ------------- Kernel 5: eighth-wave gather-aggregate (wave/node, 8 lanes x u16x8 per edge) -------
__global__ __launch_bounds__(256) void aggregate(const int* __restrict__ offs,
                                                 const int2* __restrict__ csr,
                                                 const unsigned short* __restrict__ zb,
                                                 float* __restrict__ out, int n) {
    int node = blockIdx.x * 4 + (threadIdx.x >> 6);
    int lane = threadIdx.x & 63;
    if (node >= n) return;
    const int q = lane >> 3;   // edge slot 0..7
    const int l = lane & 7;    // 8 lanes cover the 64-col row as u16x8 (16B/lane)
    int beg = offs[node];
    int end = offs[node + 1];

    float acc[8] = {};
    float s = 0.f;
    int j = beg + q;
    for (; j + 8 < end; j += 16) {  // 2 edges per slot in flight (16 per wave)
        int2 e0 = csr[j];
        int2 e1 = csr[j + 8];
        float w0 = __int_as_float(e0.y);
        float w1 = __int_as_float(e1.y);
        u16x8 z0 = *(const u16x8*)&zb[(size_t)e0.x * OUT_DIM + l * 8];
        u16x8 z1 = *(const u16x8*)&zb[(size_t)e1.x * OUT_DIM + l * 8];
        #pragma unroll
        for (int k = 0; k < 8; ++k) {
            acc[k] = fmaf(w0, b2f(z0[k]), acc[k]);
            acc[k] = fmaf(w1, b2f(z1[k]), acc[k]);
        }
        s += w0 + w1;
    }
    for (; j < end; j += 8) {
        int2 e0 = csr[j];
        float w0 = __int_as_float(e0.y);
        u16x8 z0 = *(const u16x8*)&zb[(size_t)e0.x * OUT_DIM + l * 8];
        #pragma unroll
        for (int k = 0; k < 8; ++k) acc[k] = fmaf(w0, b2f(z0[k]), acc[k]);
        s += w0;
    }
    // cross-slot reduce (lanes with same l sum over the 8 edge slots)
    #pragma unroll
    for (int o = 8; o < 64; o <<= 1) {
        #pragma unroll
        for (int k = 0; k < 8; ++k) acc[k] += __shfl_xor(acc[k], o);
        s += __shfl_xor(s, o);
    }
    if (q == 0) {
        float inv = (end > beg) ? 1.0f / s : 0.f;  // isolated node -> 0
        float4 o0 = make_float4(acc[0] * inv, acc[1] * inv, acc[2] * inv, acc[3] * inv);
        float4 o1 = make_float4(acc[4] * inv, acc[5] * inv, acc[6] * inv, acc[7] * inv);
        *(float4*)&out[(size_t)node * OUT_DIM + l * 8] = o0;
        *(float4*)&out[(size_t)node * OUT_DIM + l * 8 + 4] = o1;
    }
}

extern "C" void kernel_launch(void* const* d_in, const int* in_sizes, int n_in,
                              void* d_out, int out_size, void* d_ws, size_t ws_size,
                              hipStream_t stream) {
    const float* h   = (const float*)d_in[0];
    const int*   src = (const int*)d_in[1];
    const int*   dst = (const int*)d_in[2];
    const float* W   = (const float*)d_in[3];
    const float* a   = (const float*)d_in[4];
    float* out = (float*)d_out;

    const int n = in_sizes[0] / IN_DIM;
    const int E = in_sizes[1];
    const int nb = (n + SCAN_CHUNK - 1) / SCAN_CHUNK;  // 25 for n=50000

    char* ws = (char*)d_ws;
    size_t off_b = 0;
    auto alloc = [&](size_t bytes) -> void* {
        void* p = ws + off_b;
        off_b += (bytes + 255) & ~(size_t)255;
        return p;
    };
    unsigned short* zb    = (unsigned short*)alloc((size_t)n * OUT_DIM * sizeof(unsigned short));
    float*          s_src = (float*)alloc((size_t)n * sizeof(float));
    float*          s_dst = (float*)alloc((size_t)n * sizeof(float));
    int*            deg   = (int*)alloc((size_t)(n + 64) * sizeof(int));  // deg[n] + ticket + flag
    int*            ticket= deg + n;
    int*            flag  = deg + n + 1;
    int*            offs  = (int*)alloc((size_t)(n + 1) * sizeof(int));
    int*            rank  = (int*)alloc((size_t)E * sizeof(int));
    int*            bsum  = (int*)alloc(256 * sizeof(int));
    int*            ebase = (int*)alloc(256 * sizeof(int));
    int2*           csr   = (int2*)alloc((size_t)E * sizeof(int2));

    const int ndeg = n + 64;  // zeroed inside gemm_mfma (covers ticket + flag)

    gemm_mfma<<<(n + 63) / 64, 256, 0, stream>>>(h, W, a, zb, s_src, s_dst, deg, ndeg, n);
    count_deg<<<(E / 4 + 255) / 256, 256, 0, stream>>>(dst, deg, rank, E);
    scan_fused<<<nb, 256, 0, stream>>>(deg, bsum, ebase, offs, ticket, flag, n, nb);
    scatter_csr<<<(E / 4 + 255) / 256, 256, 0, stream>>>(src, dst, s_src, s_dst, offs,
                                                         rank, csr, E);
    aggregate<<<(n + 3) / 4, 256, 0, stream>>>(offs, csr, zb, out, n);
}